// Round 2
// baseline (99.247 us; speedup 1.0000x reference)
//
#include <hip/hip_runtime.h>
#include <math.h>

// ---------------------------------------------------------------------------
// HyperMTANPro fused hypernetwork-MLP, MI355X (gfx950).
//
// Refold: pbmm(x, hx@Wh+bh) + (hx@Wb+bb)  ==  [y (x) xa] @ Wfold
//   y  = [hyper_x, 1]            (H=11 slots)
//   xa = [x, 1, 0-pad]           (NP slots, mult of 8)
//   k  = h*NP + n,  K padded to mult of 32
// Weights are packed once per launch (prep_kernel) into fp16 MFMA B-fragment
// streaming order: frag(s, c, lane) holds W'[k = s*32+(lane>>4)*8+i][col =
// c*16+(lane&15)], contiguous 16B per lane -> global_load_dwordx4.
//
// Main kernel: 64 blocks x 512 threads (8 waves); block owns 16 samples and
// runs the whole net out of LDS. MFMA m=sample row, n=out col, fp32 accum.
// A-frag built in-register: ds_read_b128 of xa + v_pk_mul_f16 by y[h].
// H==1 layers are plain GEMMs: A-frag is xa directly (NO y-scale) — this was
// round-1's bug (g1 was scaled by hyper_x[b,0]).
// ---------------------------------------------------------------------------

typedef _Float16 f16x8 __attribute__((ext_vector_type(8)));
typedef float    f32x4 __attribute__((ext_vector_type(4)));

#define XSLOT 296   // halfs per xa row in LDS (mult of 8; 592B stride -> ~2-way banks)

// packed-blob half offsets
#define OFF_G1 0
#define OFF_L0 73728
#define OFF_L1 446464
#define OFF_L2 638976
#define OFF_L3 831488
#define OFF_LE 1216512
#define OFF_LL 1402880
#define TOTAL_CHUNKS 176960   // 16-byte fragments across all layers

// ---------------------------- weight prep ---------------------------------

template<int N, int NP, int KP, int Mp, int M, int H>
__device__ __forceinline__ void prep_layer(int lci,
    const float* __restrict__ Wm, const float* __restrict__ bm,
    const float* __restrict__ Wb, const float* __restrict__ bb,
    _Float16* __restrict__ dst)
{
    constexpr int CT = Mp / 16;           // col tiles (power of 2)
    const int l  = lci & 63;
    const int sc = lci >> 6;
    const int c  = sc & (CT - 1);
    const int s  = sc / CT;
    const int col = c * 16 + (l & 15);
    const int k0  = s * 32 + ((l >> 4) << 3);
    const int h   = k0 / NP;              // compile-time NP -> magic mul
    const int n0  = k0 - h * NP;

    f16x8 v;
    #pragma unroll
    for (int i = 0; i < 8; ++i) {
        const int n = n0 + i;
        float w = 0.f;
        if (h < H && col < M && n <= N) {
            if (H == 11 && h < 10)
                w = (n < N) ? Wm[h * (N * M) + n * M + col] : Wb[h * M + col];
            else  // h == 10 (gen-bias rows) or the H==1 plain-GEMM layer
                w = (n < N) ? bm[n * M + col] : bb[col];
        }
        v[i] = (_Float16)w;
    }
    *(f16x8*)(dst + (size_t)lci * 8) = v;
}

__global__ __launch_bounds__(256) void prep_kernel(
    const float* G1w,  const float* G1b,
    const float* Wmw0, const float* bmw0, const float* Wmb0, const float* bmb0,
    const float* Wmw1, const float* bmw1, const float* Wmb1, const float* bmb1,
    const float* Wmw2, const float* bmw2, const float* Wmb2, const float* bmb2,
    const float* Wmw3, const float* bmw3, const float* Wmb3, const float* bmb3,
    const float* Wew,  const float* bew,  const float* Web,  const float* beb,
    const float* Wlw,  const float* blw,  const float* Wlb,  const float* blb,
    _Float16* __restrict__ Wp)
{
    const int ci = blockIdx.x * 256 + threadIdx.x;
    if (ci >= TOTAL_CHUNKS) return;
    // chunk ranges: g1 9216 | L0 46592 | L1 24064 | L2 24064 | L3 48128 | LE 23296 | LL 1600
    if (ci < 9216)
        prep_layer<256,264, 288,256,256, 1>(ci,          nullptr, G1w, nullptr, G1b, Wp + OFF_G1);
    else if (ci < 55808)
        prep_layer<256,264,2912,128,128,11>(ci - 9216,   Wmw0, bmw0, Wmb0, bmb0, Wp + OFF_L0);
    else if (ci < 79872)
        prep_layer<128,136,1504,128,128,11>(ci - 55808,  Wmw1, bmw1, Wmb1, bmb1, Wp + OFF_L1);
    else if (ci < 103936)
        prep_layer<128,136,1504,128,128,11>(ci - 79872,  Wmw2, bmw2, Wmb2, bmb2, Wp + OFF_L2);
    else if (ci < 152064)
        prep_layer<128,136,1504,256,256,11>(ci - 103936, Wmw3, bmw3, Wmb3, bmb3, Wp + OFF_L3);
    else if (ci < 175360)
        prep_layer<256,264,2912, 64, 64,11>(ci - 152064, Wew,  bew,  Web,  beb,  Wp + OFF_LE);
    else
        prep_layer< 64, 72, 800, 16,  8,11>(ci - 175360, Wlw,  blw,  Wlb,  blb,  Wp + OFF_LL);
}

// ---------------------------- fused forward -------------------------------

template<int M>
__device__ __forceinline__ void pad_fill(_Float16* xa, int tid)
{
    // slot M = 1.0 (augment), slots (M, XSLOT) = 0
    constexpr int CNT = XSLOT - M;
    for (int idx = tid; idx < 16 * CNT; idx += 512) {
        const int row = idx / CNT;
        const int o   = idx - row * CNT;
        xa[row * XSLOT + M + o] = (o == 0) ? (_Float16)1.f : (_Float16)0.f;
    }
}

template<int NP, int KP, int CT, int H, int NACC>
__device__ __forceinline__ void run_layer(
    const _Float16* __restrict__ Wp,
    const _Float16* __restrict__ xaIn,   // LDS [16][XSLOT]
    const _Float16* __restrict__ y1,     // LDS [16][12]
    f32x4* acc, int wave, int lane)
{
    if (CT < 8 && wave >= CT) return;    // idle waves skip
    const int r = lane & 15;
    const int q = lane >> 4;
    f32x4 zero4 = {0.f, 0.f, 0.f, 0.f};
    #pragma unroll
    for (int j = 0; j < NACC; ++j) acc[j] = zero4;

    const _Float16* xrow = xaIn + r * XSLOT;
    #pragma unroll 2
    for (int s = 0; s < KP / 32; ++s) {
        const int k0 = s * 32 + (q << 3);
        const int h  = k0 / NP;
        f16x8 a;
        if (h < H) {
            const int n0 = k0 - h * NP;
            f16x8 xv = *(const f16x8*)(xrow + n0);
            if (H == 1) {
                a = xv;                  // plain GEMM: no hyper scale
            } else {
                const _Float16 ys = y1[r * 12 + h];
                f16x8 y8 = {ys, ys, ys, ys, ys, ys, ys, ys};
                a = xv * y8;             // 4x v_pk_mul_f16
            }
        } else {
            f16x8 z8 = {0, 0, 0, 0, 0, 0, 0, 0};
            a = z8;
        }
        #pragma unroll
        for (int j = 0; j < NACC; ++j) {
            const int c = wave + 8 * j;
            if (c < CT) {
                f16x8 b = *(const f16x8*)(Wp + ((size_t)(s * CT + c) * 64 + lane) * 8);
                acc[j] = __builtin_amdgcn_mfma_f32_16x16x32_f16(a, b, acc[j], 0, 0, 0);
            }
        }
    }
}

__global__ __launch_bounds__(512, 1) void fused_kernel(
    const float* __restrict__ hyper_x, const float* __restrict__ mlp_x,
    const float* __restrict__ G0w, const float* __restrict__ G0b,
    const _Float16* __restrict__ Wp, float* __restrict__ out)
{
    __shared__ __align__(16) _Float16 xaA[16 * XSLOT];
    __shared__ __align__(16) _Float16 xaB[16 * XSLOT];
    __shared__ __align__(16) _Float16 g1b[16 * XSLOT];
    __shared__ _Float16 y1[16 * 12];

    const int tid  = threadIdx.x;
    const int lane = tid & 63;
    const int wave = tid >> 6;
    const int b0   = blockIdx.x * 16;
    const int r = lane & 15, q = lane >> 4;

    // stage y = [hyper_x, 1]
    if (tid < 160) {
        const int b = tid / 10, h = tid - b * 10;
        y1[b * 12 + h] = (_Float16)hyper_x[(b0 + b) * 10 + h];
    }
    if (tid < 16) { y1[tid * 12 + 10] = (_Float16)1.f; y1[tid * 12 + 11] = (_Float16)0.f; }

    // g0 = relu(mlp_x @ G0w + G0b)  -> xaA  (VALU, K=9 tiny)
    {
        const int b  = (tid >> 4) & 15;
        const int hi = tid >> 8;
        float mx[9];
        #pragma unroll
        for (int n = 0; n < 9; ++n) mx[n] = mlp_x[(b0 + b) * 9 + n];
        #pragma unroll
        for (int it = 0; it < 8; ++it) {
            const int j = (tid & 15) + 16 * it + 128 * hi;
            float acc = G0b[j];
            #pragma unroll
            for (int n = 0; n < 9; ++n) acc = fmaf(mx[n], G0w[n * 256 + j], acc);
            xaA[b * XSLOT + j] = (_Float16)fmaxf(acc, 0.f);
        }
    }
    pad_fill<256>(xaA, tid);
    __syncthreads();

    // g1 = relu(g0 @ G1w + G1b): xaA -> g1b   (H=1 plain GEMM)
    {
        f32x4 acc[2];
        run_layer<264, 288, 16, 1, 2>(Wp + OFF_G1, xaA, y1, acc, wave, lane);
        #pragma unroll
        for (int j = 0; j < 2; ++j) {
            const int c = wave + 8 * j;
            #pragma unroll
            for (int t = 0; t < 4; ++t)
                g1b[(q * 4 + t) * XSLOT + c * 16 + r] = (_Float16)fmaxf(acc[j][t], 0.f);
        }
    }
    // no barrier: L0 reads xaA (unchanged), writes xaB (disjoint from g1b)

    // L0 mask layer 0: xaA -> xaB, relu
    {
        f32x4 acc[1];
        run_layer<264, 2912, 8, 11, 1>(Wp + OFF_L0, xaA, y1, acc, wave, lane);
        #pragma unroll
        for (int t = 0; t < 4; ++t)
            xaB[(q * 4 + t) * XSLOT + wave * 16 + r] = (_Float16)fmaxf(acc[0][t], 0.f);
        pad_fill<128>(xaB, tid);
    }
    __syncthreads();

    // L1: xaB -> xaA, relu
    {
        f32x4 acc[1];
        run_layer<136, 1504, 8, 11, 1>(Wp + OFF_L1, xaB, y1, acc, wave, lane);
        #pragma unroll
        for (int t = 0; t < 4; ++t)
            xaA[(q * 4 + t) * XSLOT + wave * 16 + r] = (_Float16)fmaxf(acc[0][t], 0.f);
        pad_fill<128>(xaA, tid);
    }
    __syncthreads();

    // L2: xaA -> xaB, relu
    {
        f32x4 acc[1];
        run_layer<136, 1504, 8, 11, 1>(Wp + OFF_L2, xaA, y1, acc, wave, lane);
        #pragma unroll
        for (int t = 0; t < 4; ++t)
            xaB[(q * 4 + t) * XSLOT + wave * 16 + r] = (_Float16)fmaxf(acc[0][t], 0.f);
        pad_fill<128>(xaB, tid);
    }
    __syncthreads();

    // L3 mask: xaB -> xaA, sigmoid(.) * g1
    {
        f32x4 acc[2];
        run_layer<136, 1504, 16, 11, 2>(Wp + OFF_L3, xaB, y1, acc, wave, lane);
        #pragma unroll
        for (int j = 0; j < 2; ++j) {
            const int c = wave + 8 * j;
            #pragma unroll
            for (int t = 0; t < 4; ++t) {
                const int row = q * 4 + t, col = c * 16 + r;
                float v = acc[j][t];
                v = 1.f / (1.f + __expf(-v));
                v *= (float)g1b[row * XSLOT + col];
                xaA[row * XSLOT + col] = (_Float16)v;
            }
        }
        pad_fill<256>(xaA, tid);
    }
    __syncthreads();

    // LE extractor: xaA -> xaB, relu  (CT=4: waves 4-7 idle)
    {
        f32x4 acc[1];
        run_layer<264, 2912, 4, 11, 1>(Wp + OFF_LE, xaA, y1, acc, wave, lane);
        if (wave < 4) {
            #pragma unroll
            for (int t = 0; t < 4; ++t)
                xaB[(q * 4 + t) * XSLOT + wave * 16 + r] = (_Float16)fmaxf(acc[0][t], 0.f);
        }
        pad_fill<64>(xaB, tid);
    }
    __syncthreads();

    // LL last: xaB -> out (f32, no activation; cols 8..15 are padding)
    {
        f32x4 acc[1];
        run_layer<72, 800, 1, 11, 1>(Wp + OFF_LL, xaB, y1, acc, wave, lane);
        if (wave == 0 && r < 8) {
            #pragma unroll
            for (int t = 0; t < 4; ++t)
                out[(size_t)(b0 + q * 4 + t) * 8 + r] = acc[0][t];
        }
    }
}

// ---------------------------- launch ---------------------------------------

extern "C" void kernel_launch(void* const* d_in, const int* in_sizes, int n_in,
                              void* d_out, int out_size, void* d_ws, size_t ws_size,
                              hipStream_t stream)
{
    const float* hyper_x = (const float*)d_in[0];
    const float* mlp_x   = (const float*)d_in[1];
    const float* G0w     = (const float*)d_in[2];
    const float* G0b     = (const float*)d_in[3];
    _Float16* Wp = (_Float16*)d_ws;   // 2,831,360 B packed fp16 weights

    prep_kernel<<<(TOTAL_CHUNKS + 255) / 256, 256, 0, stream>>>(
        (const float*)d_in[4],  (const float*)d_in[5],
        (const float*)d_in[6],  (const float*)d_in[7],  (const float*)d_in[8],  (const float*)d_in[9],
        (const float*)d_in[10], (const float*)d_in[11], (const float*)d_in[12], (const float*)d_in[13],
        (const float*)d_in[14], (const float*)d_in[15], (const float*)d_in[16], (const float*)d_in[17],
        (const float*)d_in[18], (const float*)d_in[19], (const float*)d_in[20], (const float*)d_in[21],
        (const float*)d_in[22], (const float*)d_in[23], (const float*)d_in[24], (const float*)d_in[25],
        (const float*)d_in[26], (const float*)d_in[27], (const float*)d_in[28], (const float*)d_in[29],
        Wp);

    fused_kernel<<<64, 512, 0, stream>>>(hyper_x, mlp_x, G0w, G0b, Wp, (float*)d_out);
}

// Round 3
// 52.784 us; speedup vs baseline: 1.8803x; 1.8803x over previous
//
#include <hip/hip_runtime.h>
#include <math.h>

// ---------------------------------------------------------------------------
// HyperMTANPro fused hypernetwork-MLP, MI355X (gfx950) — round 3.
//
// Refold: pbmm(x, hx@Wh+bh) + (hx@Wb+bb)  ==  [y (x) xa] @ Wfold
//   y = [hyper_x, 1] (H=11), xa = [x, 1, 0-pad] (NP slots, NP multiple of 32)
//   k = h*NP + n  (h-major; NPS = NP/32 k-steps per h, exact)
// prep_kernel packs all layer weights to fp16 MFMA B-frag streaming order:
//   frag(s,c): lane l elem i = W'[k=s*32+(l>>4)*8+i][col=c*16+(l&15)]
//
// fused_kernel: 64 blocks x 1024 threads (16 waves), block owns 16 samples,
// entire net in LDS. Per layer, 16 wave-tasks = col-tiles x K-split; K-split
// partials (f32) land in LDS `part` and are reduced during activation.
// Fully-unrolled h-major MFMA loops (compile-time offsets), x-frags hoisted
// to VGPRs once per layer, 2 interleaved accumulators to halve dep chains.
// ---------------------------------------------------------------------------

typedef _Float16 f16x8 __attribute__((ext_vector_type(8)));
typedef float    f32x4 __attribute__((ext_vector_type(4)));

#define XSLOT 296   // halfs per xa row in LDS (>= NP_max=288; 592B row stride)

// packed-blob half offsets
#define OFF_G1 0
#define OFF_L0 73728
#define OFF_L1 479232
#define OFF_L2 704512
#define OFF_L3 929792
#define OFF_LE 1380352
#define OFF_LL 1583104
#define TOTAL_CHUNKS 200000   // 16-byte fragments; blob = 3.2 MB fp16

// ---------------------------- weight prep ---------------------------------

template<int N, int NP, int Mp, int M, int H>
__device__ __forceinline__ void prep_layer(int lci,
    const float* __restrict__ Wm, const float* __restrict__ bm,
    const float* __restrict__ Wb, const float* __restrict__ bb,
    _Float16* __restrict__ dst)
{
    constexpr int CT = Mp / 16;           // col tiles (power of 2, or 1)
    const int l  = lci & 63;
    const int sc = lci >> 6;
    const int c  = sc & (CT - 1);
    const int s  = sc / CT;
    const int col = c * 16 + (l & 15);
    const int k0  = s * 32 + ((l >> 4) << 3);
    const int h   = k0 / NP;              // NP compile-time (h < H always)
    const int n0  = k0 - h * NP;

    f16x8 v;
    #pragma unroll
    for (int i = 0; i < 8; ++i) {
        const int n = n0 + i;
        float w = 0.f;
        if (col < M && n <= N) {
            if (H == 11 && h < 10)
                w = (n < N) ? Wm[h * (N * M) + n * M + col] : Wb[h * M + col];
            else  // h == 10 (gen-bias row, y=1) or the H==1 plain-GEMM layer
                w = (n < N) ? bm[n * M + col] : bb[col];
        }
        v[i] = (_Float16)w;
    }
    *(f16x8*)(dst + (size_t)lci * 8) = v;
}

__global__ __launch_bounds__(256) void prep_kernel(
    const float* G1w,  const float* G1b,
    const float* Wmw0, const float* bmw0, const float* Wmb0, const float* bmb0,
    const float* Wmw1, const float* bmw1, const float* Wmb1, const float* bmb1,
    const float* Wmw2, const float* bmw2, const float* Wmb2, const float* bmb2,
    const float* Wmw3, const float* bmw3, const float* Wmb3, const float* bmb3,
    const float* Wew,  const float* bew,  const float* Web,  const float* beb,
    const float* Wlw,  const float* blw,  const float* Wlb,  const float* blb,
    _Float16* __restrict__ Wp)
{
    const int ci = blockIdx.x * 256 + threadIdx.x;
    if (ci >= TOTAL_CHUNKS) return;
    // chunks: g1 9216 | L0 50688 | L1 28160 | L2 28160 | L3 56320 | LE 25344 | LL 2112
    if (ci < 9216)
        prep_layer<256,288,256,256, 1>(ci,          nullptr, G1w, nullptr, G1b, Wp + OFF_G1);
    else if (ci < 59904)
        prep_layer<256,288,128,128,11>(ci - 9216,   Wmw0, bmw0, Wmb0, bmb0, Wp + OFF_L0);
    else if (ci < 88064)
        prep_layer<128,160,128,128,11>(ci - 59904,  Wmw1, bmw1, Wmb1, bmb1, Wp + OFF_L1);
    else if (ci < 116224)
        prep_layer<128,160,128,128,11>(ci - 88064,  Wmw2, bmw2, Wmb2, bmb2, Wp + OFF_L2);
    else if (ci < 172544)
        prep_layer<128,160,256,256,11>(ci - 116224, Wmw3, bmw3, Wmb3, bmb3, Wp + OFF_L3);
    else if (ci < 197888)
        prep_layer<256,288, 64, 64,11>(ci - 172544, Wew,  bew,  Web,  beb,  Wp + OFF_LE);
    else
        prep_layer< 64, 96, 16,  8,11>(ci - 197888, Wlw,  blw,  Wlb,  blb,  Wp + OFF_LL);
}

// ---------------------------- fused forward -------------------------------

template<int M>
__device__ __forceinline__ void pad_fill(_Float16* xa, int tid)
{
    // slot M = 1.0 (augment), slots (M, XSLOT) = 0
    constexpr int CNT = XSLOT - M;
    for (int idx = tid; idx < 16 * CNT; idx += 1024) {
        const int row = idx / CNT;
        const int o   = idx - row * CNT;
        xa[row * XSLOT + M + o] = (o == 0) ? (_Float16)1.f : (_Float16)0.f;
    }
}

// one wave-task: col-tile cw, hyper-slots [H0,H1), fully unrolled.
template<int NPS, int CT, int H0, int H1, bool SCALE>
__device__ __forceinline__ f32x4 layer_mfma(
    const _Float16* __restrict__ Wp,     // layer blob base
    const _Float16* __restrict__ xaIn,   // LDS [16][XSLOT]
    const _Float16* __restrict__ y1,     // LDS [16][12]
    int cw, int lane)
{
    const int r = lane & 15, q = lane >> 4;
    // hoist x fragments (identical across h): NPS x f16x8
    f16x8 xv[NPS];
    const _Float16* xrow = xaIn + r * XSLOT + q * 8;
    #pragma unroll
    for (int j = 0; j < NPS; ++j) xv[j] = *(const f16x8*)(xrow + j * 32);

    f32x4 acc0 = {0.f, 0.f, 0.f, 0.f}, acc1 = acc0;
    const _Float16* wbase = Wp + ((size_t)cw * 64 + lane) * 8;
    #pragma unroll
    for (int h = H0; h < H1; ++h) {
        _Float16 ys = (_Float16)1.f;
        if (SCALE) ys = y1[r * 12 + h];
        #pragma unroll
        for (int j = 0; j < NPS; ++j) {
            f16x8 a = xv[j];
            if (SCALE) {
                f16x8 y8 = {ys, ys, ys, ys, ys, ys, ys, ys};
                a = a * y8;
            }
            f16x8 b = *(const f16x8*)(wbase + (size_t)((h * NPS + j) * CT) * 512);
            if (((h - H0) * NPS + j) & 1)
                acc1 = __builtin_amdgcn_mfma_f32_16x16x32_f16(a, b, acc1, 0, 0, 0);
            else
                acc0 = __builtin_amdgcn_mfma_f32_16x16x32_f16(a, b, acc0, 0, 0, 0);
        }
    }
    return acc0 + acc1;
}

__global__ __launch_bounds__(1024, 1) void fused_kernel(
    const float* __restrict__ hyper_x, const float* __restrict__ mlp_x,
    const float* __restrict__ G0w, const float* __restrict__ G0b,
    const _Float16* __restrict__ Wp, float* __restrict__ out)
{
    __shared__ __align__(16) _Float16 xaA[16 * XSLOT];
    __shared__ __align__(16) _Float16 xaB[16 * XSLOT];
    __shared__ __align__(16) _Float16 g1b[16 * XSLOT];
    __shared__ float part[16][288];      // [wave][row*18 + col], row stride 18
    __shared__ _Float16 y1[16 * 12];
    __shared__ float mlx[144];

    const int tid  = threadIdx.x;
    const int lane = tid & 63;
    const int wave = tid >> 6;
    const int b0   = blockIdx.x * 16;
    const int r = lane & 15, q = lane >> 4;

    // stage y = [hyper_x, 1] and mlp_x
    if (tid < 160) {
        const int b = tid / 10, h = tid - b * 10;
        y1[b * 12 + h] = (_Float16)hyper_x[(b0 + b) * 10 + h];
    }
    if (tid < 16) { y1[tid * 12 + 10] = (_Float16)1.f; y1[tid * 12 + 11] = (_Float16)0.f; }
    if (tid < 144) mlx[tid] = mlp_x[b0 * 9 + tid];
    __syncthreads();

    // g0 = relu(mlp_x @ G0w + G0b) -> xaA   (wave = sample, 4 cols/thread)
    {
        float m[9];
        #pragma unroll
        for (int n = 0; n < 9; ++n) m[n] = mlx[wave * 9 + n];
        #pragma unroll
        for (int it = 0; it < 4; ++it) {
            const int j = lane + 64 * it;
            float acc = G0b[j];
            #pragma unroll
            for (int n = 0; n < 9; ++n) acc = fmaf(m[n], G0w[n * 256 + j], acc);
            xaA[wave * XSLOT + j] = (_Float16)fmaxf(acc, 0.f);
        }
    }
    pad_fill<256>(xaA, tid);
    __syncthreads();

    // g1 = relu(g0 @ G1w + G1b): xaA -> g1b   (direct, CT=16, NS=9)
    {
        f32x4 acc = layer_mfma<9, 16, 0, 1, false>(Wp + OFF_G1, xaA, y1, wave, lane);
        #pragma unroll
        for (int t = 0; t < 4; ++t)
            g1b[(q * 4 + t) * XSLOT + wave * 16 + r] = (_Float16)fmaxf(acc[t], 0.f);
    }
    // L0: xaA -> part   (CT=8, K-split 2: h 0-5 / 6-10)
    {
        const int cw = wave & 7;
        f32x4 acc = (wave >> 3)
            ? layer_mfma<9, 8, 6, 11, true>(Wp + OFF_L0, xaA, y1, cw, lane)
            : layer_mfma<9, 8, 0,  6, true>(Wp + OFF_L0, xaA, y1, cw, lane);
        #pragma unroll
        for (int t = 0; t < 4; ++t) part[wave][(q * 4 + t) * 18 + r] = acc[t];
    }
    __syncthreads();
    // reduce L0 -> xaB, relu
    #pragma unroll
    for (int ii = 0; ii < 2; ++ii) {
        const int idx = tid + ii * 1024;
        const int row = idx >> 7, col = idx & 127;
        const int cw = col >> 4, cl = col & 15;
        const float v = part[cw][row * 18 + cl] + part[cw + 8][row * 18 + cl];
        xaB[row * XSLOT + col] = (_Float16)fmaxf(v, 0.f);
    }
    pad_fill<128>(xaB, tid);
    __syncthreads();

    // L1: xaB -> part
    {
        const int cw = wave & 7;
        f32x4 acc = (wave >> 3)
            ? layer_mfma<5, 8, 6, 11, true>(Wp + OFF_L1, xaB, y1, cw, lane)
            : layer_mfma<5, 8, 0,  6, true>(Wp + OFF_L1, xaB, y1, cw, lane);
        #pragma unroll
        for (int t = 0; t < 4; ++t) part[wave][(q * 4 + t) * 18 + r] = acc[t];
    }
    __syncthreads();
    // reduce L1 -> xaA, relu
    #pragma unroll
    for (int ii = 0; ii < 2; ++ii) {
        const int idx = tid + ii * 1024;
        const int row = idx >> 7, col = idx & 127;
        const int cw = col >> 4, cl = col & 15;
        const float v = part[cw][row * 18 + cl] + part[cw + 8][row * 18 + cl];
        xaA[row * XSLOT + col] = (_Float16)fmaxf(v, 0.f);
    }
    pad_fill<128>(xaA, tid);
    __syncthreads();

    // L2: xaA -> part
    {
        const int cw = wave & 7;
        f32x4 acc = (wave >> 3)
            ? layer_mfma<5, 8, 6, 11, true>(Wp + OFF_L2, xaA, y1, cw, lane)
            : layer_mfma<5, 8, 0,  6, true>(Wp + OFF_L2, xaA, y1, cw, lane);
        #pragma unroll
        for (int t = 0; t < 4; ++t) part[wave][(q * 4 + t) * 18 + r] = acc[t];
    }
    __syncthreads();
    // reduce L2 -> xaB, relu
    #pragma unroll
    for (int ii = 0; ii < 2; ++ii) {
        const int idx = tid + ii * 1024;
        const int row = idx >> 7, col = idx & 127;
        const int cw = col >> 4, cl = col & 15;
        const float v = part[cw][row * 18 + cl] + part[cw + 8][row * 18 + cl];
        xaB[row * XSLOT + col] = (_Float16)fmaxf(v, 0.f);
    }
    pad_fill<128>(xaB, tid);
    __syncthreads();

    // L3 mask: xaB -> sigmoid(.) * g1b -> xaA   (direct, CT=16, NS=55)
    {
        f32x4 acc = layer_mfma<5, 16, 0, 11, true>(Wp + OFF_L3, xaB, y1, wave, lane);
        #pragma unroll
        for (int t = 0; t < 4; ++t) {
            const int row = q * 4 + t, col = wave * 16 + r;
            float v = acc[t];
            v = 1.f / (1.f + __expf(-v));
            v *= (float)g1b[row * XSLOT + col];
            xaA[row * XSLOT + col] = (_Float16)v;
        }
    }
    pad_fill<256>(xaA, tid);
    __syncthreads();

    // LE extractor: xaA -> part   (CT=4, K-split 4: h 0-2/3-5/6-8/9-10)
    {
        const int cw = wave & 3, kw = wave >> 2;
        f32x4 acc;
        if      (kw == 0) acc = layer_mfma<9, 4, 0,  3, true>(Wp + OFF_LE, xaA, y1, cw, lane);
        else if (kw == 1) acc = layer_mfma<9, 4, 3,  6, true>(Wp + OFF_LE, xaA, y1, cw, lane);
        else if (kw == 2) acc = layer_mfma<9, 4, 6,  9, true>(Wp + OFF_LE, xaA, y1, cw, lane);
        else              acc = layer_mfma<9, 4, 9, 11, true>(Wp + OFF_LE, xaA, y1, cw, lane);
        #pragma unroll
        for (int t = 0; t < 4; ++t) part[wave][(q * 4 + t) * 18 + r] = acc[t];
    }
    __syncthreads();
    // reduce LE -> xaB, relu (M=64)
    {
        const int row = tid >> 6, col = tid & 63;
        const int cw = col >> 4, cl = col & 15;
        const float v = part[cw][row * 18 + cl] + part[cw + 4][row * 18 + cl]
                      + part[cw + 8][row * 18 + cl] + part[cw + 12][row * 18 + cl];
        xaB[row * XSLOT + col] = (_Float16)fmaxf(v, 0.f);
    }
    pad_fill<64>(xaB, tid);
    __syncthreads();

    // LL last: xaB -> part   (CT=1, K-split 11: wave = h, NS=3)
    if (wave < 11) {
        const _Float16* xrow = xaB + r * XSLOT + q * 8;
        f16x8 xv0 = *(const f16x8*)(xrow);
        f16x8 xv1 = *(const f16x8*)(xrow + 32);
        f16x8 xv2 = *(const f16x8*)(xrow + 64);
        const _Float16 ys = y1[r * 12 + wave];
        f16x8 y8 = {ys, ys, ys, ys, ys, ys, ys, ys};
        const _Float16* wbase = Wp + OFF_LL + (size_t)(wave * 3) * 512 + lane * 8;
        f32x4 acc = {0.f, 0.f, 0.f, 0.f};
        acc = __builtin_amdgcn_mfma_f32_16x16x32_f16(xv0 * y8, *(const f16x8*)(wbase),        acc, 0, 0, 0);
        acc = __builtin_amdgcn_mfma_f32_16x16x32_f16(xv1 * y8, *(const f16x8*)(wbase + 512),  acc, 0, 0, 0);
        acc = __builtin_amdgcn_mfma_f32_16x16x32_f16(xv2 * y8, *(const f16x8*)(wbase + 1024), acc, 0, 0, 0);
        #pragma unroll
        for (int t = 0; t < 4; ++t) part[wave][(q * 4 + t) * 18 + r] = acc[t];
    }
    __syncthreads();
    // reduce LL -> out (f32, 16 rows x 8 cols)
    if (tid < 128) {
        const int row = tid >> 3, col = tid & 7;
        float v = 0.f;
        #pragma unroll
        for (int w = 0; w < 11; ++w) v += part[w][row * 18 + col];
        out[(size_t)(b0 + row) * 8 + col] = v;
    }
}

// ---------------------------- launch ---------------------------------------

extern "C" void kernel_launch(void* const* d_in, const int* in_sizes, int n_in,
                              void* d_out, int out_size, void* d_ws, size_t ws_size,
                              hipStream_t stream)
{
    const float* hyper_x = (const float*)d_in[0];
    const float* mlp_x   = (const float*)d_in[1];
    const float* G0w     = (const float*)d_in[2];
    const float* G0b     = (const float*)d_in[3];
    _Float16* Wp = (_Float16*)d_ws;   // 3.2 MB packed fp16 weights

    prep_kernel<<<(TOTAL_CHUNKS + 255) / 256, 256, 0, stream>>>(
        (const float*)d_in[4],  (const float*)d_in[5],
        (const float*)d_in[6],  (const float*)d_in[7],  (const float*)d_in[8],  (const float*)d_in[9],
        (const float*)d_in[10], (const float*)d_in[11], (const float*)d_in[12], (const float*)d_in[13],
        (const float*)d_in[14], (const float*)d_in[15], (const float*)d_in[16], (const float*)d_in[17],
        (const float*)d_in[18], (const float*)d_in[19], (const float*)d_in[20], (const float*)d_in[21],
        (const float*)d_in[22], (const float*)d_in[23], (const float*)d_in[24], (const float*)d_in[25],
        (const float*)d_in[26], (const float*)d_in[27], (const float*)d_in[28], (const float*)d_in[29],
        Wp);

    fused_kernel<<<64, 1024, 0, stream>>>(hyper_x, mlp_x, G0w, G0b, Wp, (float*)d_out);
}